// Round 12
// baseline (342.349 us; speedup 1.0000x reference)
//
#include <hip/hip_runtime.h>

#define N_NODES 50000
#define N_REL   3
#define N_EDGE  200000
#define RN      (N_REL * N_NODES)      // 150000 (relation, node) pairs for norms
#define RE      (N_REL * N_EDGE)       // 600000 edges total
#define GEMM1_BLKS 782                 // ceil(50000/64)
#define FUSE_CHUNKS 98                 // 98*8=784>=782 gemm, 98*24=2352 deg blocks
#define SF_BLOCKS 196                  // scan_fill: 196*256=50176>=N_NODES, co-resident
#define PREP_BLKS  288

typedef short bf16x8 __attribute__((ext_vector_type(8)));
typedef float f32x4  __attribute__((ext_vector_type(4)));

// ---------------- f32 -> bf16 (RNE) ----------------
__device__ __forceinline__ unsigned short f2bf(float f) {
    unsigned u = __float_as_uint(f);
    u = (u + 0x7fffu + ((u >> 16) & 1u)) >> 16;
    return (unsigned short)u;
}
__device__ __forceinline__ unsigned pack_bf2(float lo, float hi) {
    return (unsigned)f2bf(lo) | ((unsigned)f2bf(hi) << 16);
}

// ---------------- W -> fragment-linear bf16 ----------------
// B element (rel, k, n):  frag f = (rel*(ncols/16) + n/16)*4 + k/32
// ushort idx = f*512 + ((k&31)/8)*128 + (n&15)*8 + (k&7)
__device__ __forceinline__ void wtrans_one(
    const float* __restrict__ W, unsigned short* __restrict__ Wtf, int ncols, int i)
{
    int rel = i / (128 * ncols);
    int rem = i - rel * 128 * ncols;
    int k   = rem / ncols;
    int n   = rem - k * ncols;
    int f   = (rel * (ncols / 16) + (n >> 4)) * 4 + (k >> 5);
    int idx = f * 512 + ((k & 31) >> 3) * 128 + (n & 15) * 8 + (k & 7);
    Wtf[idx] = f2bf(W[i]);
}

// prep: weight convert + zero degree counters + zero spin flags
__global__ __launch_bounds__(256) void prep_kernel(
    const float* __restrict__ W1, unsigned short* __restrict__ Wt1,
    const float* __restrict__ W2, unsigned short* __restrict__ Wt2,
    float* __restrict__ zbuf, int* __restrict__ done)
{
    int i = blockIdx.x * 256 + threadIdx.x;
    if (i < 2) done[i] = 0;
    for (int q = i; q < 2 * RN; q += PREP_BLKS * 256) zbuf[q] = 0.f;
    if (i < 3 * 128 * 128) {
        wtrans_one(W1, Wt1, 128, i);
    } else {
        int j = i - 3 * 128 * 128;
        if (j < 3 * 128 * 64) wtrans_one(W2, Wt2, 64, j);
    }
}

// ---------------- LDS-light layer-1 GEMM body (16KB LDS, for fusion) ----------------
__device__ __forceinline__ void gemm1_body_light(
    const float* __restrict__ A, const unsigned short* __restrict__ Wtf,
    unsigned short* __restrict__ Y, int mt, unsigned* Ws)
{
    const int tid = threadIdx.x;
    const uint4* Wt4 = (const uint4*)Wtf;
    const int w  = tid >> 6;
    const int l  = tid & 63;
    const int g  = l >> 4;
    const int lr = l & 15;
    const int arow = mt + w * 16 + lr;
    const bool rowok = arow < N_NODES;

    bf16x8 a[4];
    #pragma unroll
    for (int kb = 0; kb < 4; ++kb) {
        float4 v0 = make_float4(0.f, 0.f, 0.f, 0.f);
        float4 v1 = make_float4(0.f, 0.f, 0.f, 0.f);
        if (rowok) {
            const float* ap = &A[(size_t)arow * 128 + kb * 32 + g * 8];
            v0 = *reinterpret_cast<const float4*>(ap);
            v1 = *reinterpret_cast<const float4*>(ap + 4);
        }
        union { unsigned u[4]; bf16x8 v; } cv;
        cv.u[0] = pack_bf2(v0.x, v0.y);
        cv.u[1] = pack_bf2(v0.z, v0.w);
        cv.u[2] = pack_bf2(v1.x, v1.y);
        cv.u[3] = pack_bf2(v1.z, v1.w);
        a[kb] = cv.v;
    }

    const int boff = (g * 16 + lr) * 4;

    #pragma unroll 1
    for (int grp = 0; grp < 6; ++grp) {
        __syncthreads();
        #pragma unroll
        for (int p = 0; p < 4; ++p) {
            uint4 v = Wt4[grp * 1024 + tid + p * 256];
            *reinterpret_cast<uint4*>(&Ws[(tid + p * 256) * 4]) = v;
        }
        __syncthreads();

        f32x4 acc[4];
        #pragma unroll
        for (int ct4 = 0; ct4 < 4; ++ct4) {
            acc[ct4] = (f32x4){0.f, 0.f, 0.f, 0.f};
            #pragma unroll
            for (int kb = 0; kb < 4; ++kb) {
                bf16x8 b = *reinterpret_cast<const bf16x8*>(
                    &Ws[(ct4 * 4 + kb) * 256 + boff]);
                acc[ct4] = __builtin_amdgcn_mfma_f32_16x16x32_bf16(a[kb], b, acc[ct4], 0, 0, 0);
            }
        }

        int rel = grp >> 1;
        int cb  = (grp & 1) * 64;
        #pragma unroll
        for (int i = 0; i < 4; ++i) {
            int grow = mt + w * 16 + g * 4 + i;
            if (grow < N_NODES) {
                size_t rowbase = ((size_t)rel * N_NODES + grow) * 128 + cb;
                #pragma unroll
                for (int ct4 = 0; ct4 < 4; ++ct4)
                    Y[rowbase + ct4 * 16 + lr] = f2bf(acc[ct4][i]);
            }
        }
    }
}

// ---------------- FUSED: layer-1 GEMM + degree count + rank, chunk-interleaved ----------------
__global__ __launch_bounds__(256) void fused_gemm1_deg(
    const float* __restrict__ x, const unsigned short* __restrict__ Wt1,
    unsigned short* __restrict__ Y,
    const int* __restrict__ src, const int* __restrict__ dst,
    float* __restrict__ odeg, float* __restrict__ ideg,
    unsigned short* __restrict__ rank)
{
    __shared__ unsigned Ws[4096];    // 16KB -> 8 blocks/CU co-tenancy

    const int c = blockIdx.x >> 5;
    const int o = blockIdx.x & 31;

    if (o < 8) {
        int gb = c * 8 + o;
        if (gb >= GEMM1_BLKS) return;
        gemm1_body_light(x, Wt1, Y, gb * 64, Ws);
    } else {
        int db = c * 24 + (o - 8);
        int i  = db * 256 + threadIdx.x;
        if (i < RE) {
            int r = i / N_EDGE;
            int s = src[i], t = dst[i];
            unsafeAtomicAdd(&odeg[r * N_NODES + s], 1.0f);
            float old = unsafeAtomicAdd(&ideg[r * N_NODES + t], 1.0f);
            rank[i] = (unsigned short)(int)old;
        }
    }
}

// ---------------- FUSED scan + fill (spin-synced, 196 co-resident blocks) ----------------
__global__ __launch_bounds__(256) void scan_fill_kernel(
    float* __restrict__ odeg, float* __restrict__ ideg,
    int* __restrict__ off, int* __restrict__ roff,
    int* __restrict__ bsums, int* __restrict__ done,
    const int* __restrict__ src, const int* __restrict__ dst,
    const unsigned short* __restrict__ rank, unsigned* __restrict__ csr)
{
    __shared__ int tsum[256];
    __shared__ int addsh;
    const int tid  = threadIdx.x;
    const int bid  = blockIdx.x;
    const int node = bid * 256 + tid;

    float c0 = 0.f, c1 = 0.f, c2 = 0.f;
    int tot = 0;
    if (node < N_NODES) {
        c0 = ideg[node];
        c1 = ideg[N_NODES + node];
        c2 = ideg[2 * N_NODES + node];
        tot = (int)c0 + (int)c1 + (int)c2;
    }
    tsum[tid] = tot;
    __syncthreads();
    #pragma unroll
    for (int d = 1; d < 256; d <<= 1) {
        int v   = tsum[tid];
        int add = (tid >= d) ? tsum[tid - d] : 0;
        __syncthreads();
        tsum[tid] = v + add;
        __syncthreads();
    }
    const int lexcl = tsum[tid] - tot;
    if (tid == 255) bsums[bid] = tsum[255];

    if (node < N_NODES) {
        ideg[node]               = rsqrtf(fmaxf(c0, 1.0f));
        ideg[N_NODES + node]     = rsqrtf(fmaxf(c1, 1.0f));
        ideg[2 * N_NODES + node] = rsqrtf(fmaxf(c2, 1.0f));
    }
    for (int q = bid * 256 + tid; q < RN; q += SF_BLOCKS * 256)
        odeg[q] = rsqrtf(fmaxf(odeg[q], 1.0f));

    __syncthreads();
    __threadfence();
    if (tid == 0) {
        __hip_atomic_fetch_add(&done[0], 1, __ATOMIC_RELEASE, __HIP_MEMORY_SCOPE_AGENT);
        while (__hip_atomic_load(&done[0], __ATOMIC_ACQUIRE, __HIP_MEMORY_SCOPE_AGENT) < SF_BLOCKS)
            __builtin_amdgcn_s_sleep(2);
    }
    __syncthreads();

    // phase2: prefix over 196 block sums
    int bv = (tid < SF_BLOCKS) ? bsums[tid] : 0;
    tsum[tid] = bv;
    __syncthreads();
    #pragma unroll
    for (int d = 1; d < 256; d <<= 1) {
        int v   = tsum[tid];
        int add = (tid >= d) ? tsum[tid - d] : 0;
        __syncthreads();
        tsum[tid] = v + add;
        __syncthreads();
    }
    if (tid == 0) addsh = (bid == 0) ? 0 : tsum[bid - 1];
    __syncthreads();

    const int gbase = lexcl + addsh;
    if (node < N_NODES) {
        off[node]                = gbase;
        roff[node]               = gbase;
        roff[N_NODES + node]     = gbase + (int)c0;
        roff[2 * N_NODES + node] = gbase + (int)c0 + (int)c1;
    }
    if (bid == 0 && tid == 0) off[N_NODES] = RE;

    __syncthreads();
    __threadfence();
    if (tid == 0) {
        __hip_atomic_fetch_add(&done[1], 1, __ATOMIC_RELEASE, __HIP_MEMORY_SCOPE_AGENT);
        while (__hip_atomic_load(&done[1], __ATOMIC_ACQUIRE, __HIP_MEMORY_SCOPE_AGENT) < SF_BLOCKS)
            __builtin_amdgcn_s_sleep(2);
    }
    __syncthreads();

    // phase3: atomic-free CSR fill (4B entries: src<<16 | bf16(weight))
    for (int q = bid * 256 + tid; q < RE; q += SF_BLOCKS * 256) {
        int r = q / N_EDGE;
        int s = src[q], t = dst[q];
        float wv = odeg[r * N_NODES + s] * ideg[r * N_NODES + t];
        int slot = roff[r * N_NODES + t] + (int)rank[q];
        csr[slot] = ((unsigned)s << 16) | (unsigned)f2bf(wv);
    }
}

// ---------------- FUSED layer 2: agg128 (-> LDS h tile) + gemm2 (MFMA from LDS) ----------------
// Block owns 64 nodes. Phase A: 4 waves aggregate 16 nodes each (unroll-8 CSR walk),
// bias+ReLU, write bf16 h row into As. Phase B: MFMA gemm (NCOLS=64, 3 groups).
// NOTE: Y2 MUST NOT alias Y1 — phase A of late blocks reads Y1 rows while early
// blocks run phase B (round-10 bug: in-place Ybf reuse raced, absmax 1.79).
__global__ __launch_bounds__(256) void layer2_fused(
    const unsigned* __restrict__ Y1, const unsigned* __restrict__ csr,
    const int* __restrict__ off, const int* __restrict__ roff,
    const float* __restrict__ b, const unsigned short* __restrict__ Wt2,
    unsigned short* __restrict__ Y2)
{
    __shared__ unsigned As[64 * 68];
    __shared__ unsigned Ws[2][4096];

    const int tid = threadIdx.x;
    const int mt  = blockIdx.x * 64;
    const uint4* Wt4 = (const uint4*)Wt2;

    // stage W group 0 early (latency hides under phase A gathers)
    #pragma unroll
    for (int p = 0; p < 4; ++p) {
        uint4 v = Wt4[tid + p * 256];
        *reinterpret_cast<uint4*>(&Ws[0][(tid + p * 256) * 4]) = v;
    }

    const int w    = tid >> 6;
    const int lane = tid & 63;

    // ---- phase A: aggregate 16 nodes per wave ----
    #pragma unroll 1
    for (int i = 0; i < 16; ++i) {
        int node = mt + w * 16 + i;
        unsigned packed = 0u;
        if (node < N_NODES) {
            int e  = off[node], end = off[node + 1];
            int r1 = roff[N_NODES + node];
            int r2 = roff[2 * N_NODES + node];
            float a0 = 0.f, a1 = 0.f;

            for (; e + 8 <= end; e += 8) {
                unsigned p[8]; unsigned y[8];
                #pragma unroll
                for (int j = 0; j < 8; ++j) p[j] = csr[e + j];
                #pragma unroll
                for (int j = 0; j < 8; ++j) {
                    int rr = (e + j >= r1) + (e + j >= r2);
                    y[j] = Y1[((size_t)rr * N_NODES + (p[j] >> 16)) * 64 + lane];
                }
                #pragma unroll
                for (int j = 0; j < 8; ++j) {
                    float wv = __uint_as_float((p[j] & 0xffffu) << 16);
                    a0 = fmaf(wv, __uint_as_float(y[j] << 16), a0);
                    a1 = fmaf(wv, __uint_as_float(y[j] & 0xffff0000u), a1);
                }
            }
            if (e + 4 <= end) {
                unsigned p[4]; unsigned y[4];
                #pragma unroll
                for (int j = 0; j < 4; ++j) p[j] = csr[e + j];
                #pragma unroll
                for (int j = 0; j < 4; ++j) {
                    int rr = (e + j >= r1) + (e + j >= r2);
                    y[j] = Y1[((size_t)rr * N_NODES + (p[j] >> 16)) * 64 + lane];
                }
                #pragma unroll
                for (int j = 0; j < 4; ++j) {
                    float wv = __uint_as_float((p[j] & 0xffffu) << 16);
                    a0 = fmaf(wv, __uint_as_float(y[j] << 16), a0);
                    a1 = fmaf(wv, __uint_as_float(y[j] & 0xffff0000u), a1);
                }
                e += 4;
            }
            for (; e < end; ++e) {
                unsigned p = csr[e];
                int rr = (e >= r1) + (e >= r2);
                unsigned y = Y1[((size_t)rr * N_NODES + (p >> 16)) * 64 + lane];
                float wv = __uint_as_float((p & 0xffffu) << 16);
                a0 = fmaf(wv, __uint_as_float(y << 16), a0);
                a1 = fmaf(wv, __uint_as_float(y & 0xffff0000u), a1);
            }

            int d = lane * 2;
            float o0 = a0 + b[d]     + b[128 + d]     + b[256 + d];
            float o1 = a1 + b[d + 1] + b[128 + d + 1] + b[256 + d + 1];
            packed = pack_bf2(fmaxf(o0, 0.f), fmaxf(o1, 0.f));
        }
        As[(w * 16 + i) * 68 + lane] = packed;
    }
    __syncthreads();

    // ---- phase B: gemm2 (NCOLS=64, NGRP=3, rel = grp) ----
    const int g  = lane >> 4;
    const int lr = lane & 15;
    const int ar = w * 16 + lr;

    bf16x8 a[4];
    #pragma unroll
    for (int kb = 0; kb < 4; ++kb)
        a[kb] = *reinterpret_cast<const bf16x8*>(&As[ar * 68 + kb * 16 + g * 4]);

    const int boff = (g * 16 + lr) * 4;
    int cur = 0;
    #pragma unroll 1
    for (int grp = 0; grp < 3; ++grp) {
        uint4 st[4];
        if (grp + 1 < 3) {
            #pragma unroll
            for (int p = 0; p < 4; ++p)
                st[p] = Wt4[(grp + 1) * 1024 + tid + p * 256];
        }

        f32x4 acc[4];
        #pragma unroll
        for (int ct4 = 0; ct4 < 4; ++ct4) {
            acc[ct4] = (f32x4){0.f, 0.f, 0.f, 0.f};
            #pragma unroll
            for (int kb = 0; kb < 4; ++kb) {
                bf16x8 bb = *reinterpret_cast<const bf16x8*>(
                    &Ws[cur][(ct4 * 4 + kb) * 256 + boff]);
                acc[ct4] = __builtin_amdgcn_mfma_f32_16x16x32_bf16(a[kb], bb, acc[ct4], 0, 0, 0);
            }
        }

        #pragma unroll
        for (int i = 0; i < 4; ++i) {
            int grow = mt + w * 16 + g * 4 + i;
            if (grow < N_NODES) {
                size_t rowbase = ((size_t)grp * N_NODES + grow) * 64;
                #pragma unroll
                for (int ct4 = 0; ct4 < 4; ++ct4)
                    Y2[rowbase + ct4 * 16 + lr] = f2bf(acc[ct4][i]);
            }
        }

        if (grp + 1 < 3) {
            #pragma unroll
            for (int p = 0; p < 4; ++p)
                *reinterpret_cast<uint4*>(&Ws[cur ^ 1][(tid + p * 256) * 4]) = st[p];
        }
        __syncthreads();
        cur ^= 1;
    }
}

// ---------------- gather aggregation, layer 2 output (D=64), 4B CSR, unroll-8 ----------------
__global__ __launch_bounds__(256) void agg64_kernel(
    const unsigned short* __restrict__ Y, const unsigned* __restrict__ csr,
    const int* __restrict__ off, const int* __restrict__ roff,
    const float* __restrict__ b, float* __restrict__ out)
{
    int wid  = (blockIdx.x * 256 + threadIdx.x) >> 6;
    int lane = threadIdx.x & 63;
    if (wid >= N_NODES) return;

    int e   = off[wid], end = off[wid + 1];
    int r1  = roff[N_NODES + wid];
    int r2  = roff[2 * N_NODES + wid];
    float a = 0.f;

    for (; e + 8 <= end; e += 8) {
        unsigned p[8]; unsigned short y[8];
        #pragma unroll
        for (int j = 0; j < 8; ++j) p[j] = csr[e + j];
        #pragma unroll
        for (int j = 0; j < 8; ++j) {
            int rr = (e + j >= r1) + (e + j >= r2);
            y[j] = Y[((size_t)rr * N_NODES + (p[j] >> 16)) * 64 + lane];
        }
        #pragma unroll
        for (int j = 0; j < 8; ++j)
            a = fmaf(__uint_as_float((p[j] & 0xffffu) << 16),
                     __uint_as_float(((unsigned)y[j]) << 16), a);
    }
    if (e + 4 <= end) {
        unsigned p[4]; unsigned short y[4];
        #pragma unroll
        for (int j = 0; j < 4; ++j) p[j] = csr[e + j];
        #pragma unroll
        for (int j = 0; j < 4; ++j) {
            int rr = (e + j >= r1) + (e + j >= r2);
            y[j] = Y[((size_t)rr * N_NODES + (p[j] >> 16)) * 64 + lane];
        }
        #pragma unroll
        for (int j = 0; j < 4; ++j)
            a = fmaf(__uint_as_float((p[j] & 0xffffu) << 16),
                     __uint_as_float(((unsigned)y[j]) << 16), a);
        e += 4;
    }
    for (; e < end; ++e) {
        unsigned p = csr[e];
        int rr = (e >= r1) + (e >= r2);
        a = fmaf(__uint_as_float((p & 0xffffu) << 16),
                 __uint_as_float(((unsigned)Y[((size_t)rr * N_NODES + (p >> 16)) * 64 + lane]) << 16), a);
    }

    float bs = b[lane] + b[64 + lane] + b[128 + lane];
    out[(size_t)wid * 64 + lane] = a + bs;
}

extern "C" void kernel_launch(void* const* d_in, const int* in_sizes, int n_in,
                              void* d_out, int out_size, void* d_ws, size_t ws_size,
                              hipStream_t stream)
{
    const float* x   = (const float*)d_in[0];   // [N,128]
    const float* W1  = (const float*)d_in[1];   // [3,128,128]
    const float* b1  = (const float*)d_in[2];   // [3,128]
    const float* W2  = (const float*)d_in[3];   // [3,128,64]
    const float* b2  = (const float*)d_in[4];   // [3,64]
    const int*   src = (const int*)d_in[5];     // [3,E]
    const int*   dst = (const int*)d_in[6];     // [3,E]
    float*       out = (float*)d_out;           // [N,64]

    // workspace layout
    char* w = (char*)d_ws;
    float* onorm  = (float*)w;                 w += (size_t)RN * 4;           // counts then norms
    float* inorm  = (float*)w;                 w += (size_t)RN * 4;           // counts then norms
    int*   off    = (int*)w;                   w += (size_t)(N_NODES + 1) * 4;
    int*   roff   = (int*)w;                   w += (size_t)RN * 4;
    int*   bsums  = (int*)w;                   w += 1024;
    int*   done   = (int*)w;                   w += 512;
    unsigned short* rank = (unsigned short*)w; w += (size_t)RE * 2;
    w = (char*)(((uintptr_t)w + 255) & ~(uintptr_t)255);
    unsigned* csr = (unsigned*)w;              w += (size_t)RE * 4;
    unsigned short* Ybf  = (unsigned short*)w; w += (size_t)N_REL * N_NODES * 128 * 2;  // layer-1 Y
    unsigned short* Y2bf = (unsigned short*)w; w += (size_t)N_REL * N_NODES * 64 * 2;   // layer-2 Y (NO alias!)
    unsigned short* Wt1  = (unsigned short*)w; w += (size_t)N_REL * 128 * 128 * 2;
    unsigned short* Wt2  = (unsigned short*)w; // 3*64*128*2

    // 0) prep: weight convert + zero counters + zero spin flags
    prep_kernel<<<PREP_BLKS, 256, 0, stream>>>(W1, Wt1, W2, Wt2, onorm, done);

    // 1) FUSED interleaved: gemm1 (x@W1 -> Ybf) + degrees + ranks
    fused_gemm1_deg<<<FUSE_CHUNKS * 32, 256, 0, stream>>>(
        x, Wt1, Ybf, src, dst, onorm, inorm, rank);

    // 2) FUSED scan+fill: off/roff + norms + atomic-free CSR fill (spin-synced)
    scan_fill_kernel<<<SF_BLOCKS, 256, 0, stream>>>(
        onorm, inorm, off, roff, bsums, done, src, dst, rank, csr);

    // 3) FUSED layer 2: agg128 (-> LDS h) + gemm2 (MFMA) -> Y2bf
    layer2_fused<<<GEMM1_BLKS, 256, 0, stream>>>(
        (const unsigned*)Ybf, csr, off, roff, b1, Wt2, Y2bf);

    // 4) final aggregation into out
    agg64_kernel<<<(N_NODES + 3) / 4, 256, 0, stream>>>(Y2bf, csr, off, roff, b2, out);
}

// Round 13
// 297.015 us; speedup vs baseline: 1.1526x; 1.1526x over previous
//
#include <hip/hip_runtime.h>

#define N_NODES 50000
#define N_REL   3
#define N_EDGE  200000
#define RN      (N_REL * N_NODES)      // 150000 (relation, node) pairs for norms
#define RE      (N_REL * N_EDGE)       // 600000 edges total
#define GEMM1_BLKS 782                 // ceil(50000/64)
#define FUSE_CHUNKS 98                 // 98*8=784>=782 gemm, 98*24=2352 deg blocks
#define SF_BLOCKS 196                  // scan_fill: 196*256=50176>=N_NODES, co-resident
#define PREP_BLKS  288

typedef short bf16x8 __attribute__((ext_vector_type(8)));
typedef float f32x4  __attribute__((ext_vector_type(4)));

// ---------------- f32 -> bf16 (RNE) ----------------
__device__ __forceinline__ unsigned short f2bf(float f) {
    unsigned u = __float_as_uint(f);
    u = (u + 0x7fffu + ((u >> 16) & 1u)) >> 16;
    return (unsigned short)u;
}
__device__ __forceinline__ unsigned pack_bf2(float lo, float hi) {
    return (unsigned)f2bf(lo) | ((unsigned)f2bf(hi) << 16);
}

// ---------------- W -> fragment-linear bf16 ----------------
// B element (rel, k, n):  frag f = (rel*(ncols/16) + n/16)*4 + k/32
// ushort idx = f*512 + ((k&31)/8)*128 + (n&15)*8 + (k&7)
__device__ __forceinline__ void wtrans_one(
    const float* __restrict__ W, unsigned short* __restrict__ Wtf, int ncols, int i)
{
    int rel = i / (128 * ncols);
    int rem = i - rel * 128 * ncols;
    int k   = rem / ncols;
    int n   = rem - k * ncols;
    int f   = (rel * (ncols / 16) + (n >> 4)) * 4 + (k >> 5);
    int idx = f * 512 + ((k & 31) >> 3) * 128 + (n & 15) * 8 + (k & 7);
    Wtf[idx] = f2bf(W[i]);
}

// prep: weight convert + zero degree counters + zero spin flags
__global__ __launch_bounds__(256) void prep_kernel(
    const float* __restrict__ W1, unsigned short* __restrict__ Wt1,
    const float* __restrict__ W2, unsigned short* __restrict__ Wt2,
    float* __restrict__ zbuf, int* __restrict__ done)
{
    int i = blockIdx.x * 256 + threadIdx.x;
    if (i < 2) done[i] = 0;
    for (int q = i; q < 2 * RN; q += PREP_BLKS * 256) zbuf[q] = 0.f;
    if (i < 3 * 128 * 128) {
        wtrans_one(W1, Wt1, 128, i);
    } else {
        int j = i - 3 * 128 * 128;
        if (j < 3 * 128 * 64) wtrans_one(W2, Wt2, 64, j);
    }
}

// ---------------- LDS-light layer-1 GEMM body (16KB LDS, for fusion) ----------------
__device__ __forceinline__ void gemm1_body_light(
    const float* __restrict__ A, const unsigned short* __restrict__ Wtf,
    unsigned short* __restrict__ Y, int mt, unsigned* Ws)
{
    const int tid = threadIdx.x;
    const uint4* Wt4 = (const uint4*)Wtf;
    const int w  = tid >> 6;
    const int l  = tid & 63;
    const int g  = l >> 4;
    const int lr = l & 15;
    const int arow = mt + w * 16 + lr;
    const bool rowok = arow < N_NODES;

    bf16x8 a[4];
    #pragma unroll
    for (int kb = 0; kb < 4; ++kb) {
        float4 v0 = make_float4(0.f, 0.f, 0.f, 0.f);
        float4 v1 = make_float4(0.f, 0.f, 0.f, 0.f);
        if (rowok) {
            const float* ap = &A[(size_t)arow * 128 + kb * 32 + g * 8];
            v0 = *reinterpret_cast<const float4*>(ap);
            v1 = *reinterpret_cast<const float4*>(ap + 4);
        }
        union { unsigned u[4]; bf16x8 v; } cv;
        cv.u[0] = pack_bf2(v0.x, v0.y);
        cv.u[1] = pack_bf2(v0.z, v0.w);
        cv.u[2] = pack_bf2(v1.x, v1.y);
        cv.u[3] = pack_bf2(v1.z, v1.w);
        a[kb] = cv.v;
    }

    const int boff = (g * 16 + lr) * 4;

    #pragma unroll 1
    for (int grp = 0; grp < 6; ++grp) {
        __syncthreads();
        #pragma unroll
        for (int p = 0; p < 4; ++p) {
            uint4 v = Wt4[grp * 1024 + tid + p * 256];
            *reinterpret_cast<uint4*>(&Ws[(tid + p * 256) * 4]) = v;
        }
        __syncthreads();

        f32x4 acc[4];
        #pragma unroll
        for (int ct4 = 0; ct4 < 4; ++ct4) {
            acc[ct4] = (f32x4){0.f, 0.f, 0.f, 0.f};
            #pragma unroll
            for (int kb = 0; kb < 4; ++kb) {
                bf16x8 b = *reinterpret_cast<const bf16x8*>(
                    &Ws[(ct4 * 4 + kb) * 256 + boff]);
                acc[ct4] = __builtin_amdgcn_mfma_f32_16x16x32_bf16(a[kb], b, acc[ct4], 0, 0, 0);
            }
        }

        int rel = grp >> 1;
        int cb  = (grp & 1) * 64;
        #pragma unroll
        for (int i = 0; i < 4; ++i) {
            int grow = mt + w * 16 + g * 4 + i;
            if (grow < N_NODES) {
                size_t rowbase = ((size_t)rel * N_NODES + grow) * 128 + cb;
                #pragma unroll
                for (int ct4 = 0; ct4 < 4; ++ct4)
                    Y[rowbase + ct4 * 16 + lr] = f2bf(acc[ct4][i]);
            }
        }
    }
}

// ---------------- FUSED: layer-1 GEMM + degree count + rank, chunk-interleaved ----------------
__global__ __launch_bounds__(256) void fused_gemm1_deg(
    const float* __restrict__ x, const unsigned short* __restrict__ Wt1,
    unsigned short* __restrict__ Y,
    const int* __restrict__ src, const int* __restrict__ dst,
    float* __restrict__ odeg, float* __restrict__ ideg,
    unsigned short* __restrict__ rank)
{
    __shared__ unsigned Ws[4096];    // 16KB -> 8 blocks/CU co-tenancy

    const int c = blockIdx.x >> 5;
    const int o = blockIdx.x & 31;

    if (o < 8) {
        int gb = c * 8 + o;
        if (gb >= GEMM1_BLKS) return;
        gemm1_body_light(x, Wt1, Y, gb * 64, Ws);
    } else {
        int db = c * 24 + (o - 8);
        int i  = db * 256 + threadIdx.x;
        if (i < RE) {
            int r = i / N_EDGE;
            int s = src[i], t = dst[i];
            unsafeAtomicAdd(&odeg[r * N_NODES + s], 1.0f);
            float old = unsafeAtomicAdd(&ideg[r * N_NODES + t], 1.0f);
            rank[i] = (unsigned short)(int)old;
        }
    }
}

// ---------------- FUSED scan + fill (spin-synced, 196 co-resident blocks) ----------------
__global__ __launch_bounds__(256) void scan_fill_kernel(
    float* __restrict__ odeg, float* __restrict__ ideg,
    int* __restrict__ off, int* __restrict__ roff,
    int* __restrict__ bsums, int* __restrict__ done,
    const int* __restrict__ src, const int* __restrict__ dst,
    const unsigned short* __restrict__ rank, unsigned* __restrict__ csr)
{
    __shared__ int tsum[256];
    __shared__ int addsh;
    const int tid  = threadIdx.x;
    const int bid  = blockIdx.x;
    const int node = bid * 256 + tid;

    float c0 = 0.f, c1 = 0.f, c2 = 0.f;
    int tot = 0;
    if (node < N_NODES) {
        c0 = ideg[node];
        c1 = ideg[N_NODES + node];
        c2 = ideg[2 * N_NODES + node];
        tot = (int)c0 + (int)c1 + (int)c2;
    }
    tsum[tid] = tot;
    __syncthreads();
    #pragma unroll
    for (int d = 1; d < 256; d <<= 1) {
        int v   = tsum[tid];
        int add = (tid >= d) ? tsum[tid - d] : 0;
        __syncthreads();
        tsum[tid] = v + add;
        __syncthreads();
    }
    const int lexcl = tsum[tid] - tot;
    if (tid == 255) bsums[bid] = tsum[255];

    if (node < N_NODES) {
        ideg[node]               = rsqrtf(fmaxf(c0, 1.0f));
        ideg[N_NODES + node]     = rsqrtf(fmaxf(c1, 1.0f));
        ideg[2 * N_NODES + node] = rsqrtf(fmaxf(c2, 1.0f));
    }
    for (int q = bid * 256 + tid; q < RN; q += SF_BLOCKS * 256)
        odeg[q] = rsqrtf(fmaxf(odeg[q], 1.0f));

    __syncthreads();
    __threadfence();
    if (tid == 0) {
        __hip_atomic_fetch_add(&done[0], 1, __ATOMIC_RELEASE, __HIP_MEMORY_SCOPE_AGENT);
        while (__hip_atomic_load(&done[0], __ATOMIC_ACQUIRE, __HIP_MEMORY_SCOPE_AGENT) < SF_BLOCKS)
            __builtin_amdgcn_s_sleep(2);
    }
    __syncthreads();

    // phase2: prefix over 196 block sums
    int bv = (tid < SF_BLOCKS) ? bsums[tid] : 0;
    tsum[tid] = bv;
    __syncthreads();
    #pragma unroll
    for (int d = 1; d < 256; d <<= 1) {
        int v   = tsum[tid];
        int add = (tid >= d) ? tsum[tid - d] : 0;
        __syncthreads();
        tsum[tid] = v + add;
        __syncthreads();
    }
    if (tid == 0) addsh = (bid == 0) ? 0 : tsum[bid - 1];
    __syncthreads();

    const int gbase = lexcl + addsh;
    if (node < N_NODES) {
        off[node]                = gbase;
        roff[node]               = gbase;
        roff[N_NODES + node]     = gbase + (int)c0;
        roff[2 * N_NODES + node] = gbase + (int)c0 + (int)c1;
    }
    if (bid == 0 && tid == 0) off[N_NODES] = RE;

    __syncthreads();
    __threadfence();
    if (tid == 0) {
        __hip_atomic_fetch_add(&done[1], 1, __ATOMIC_RELEASE, __HIP_MEMORY_SCOPE_AGENT);
        while (__hip_atomic_load(&done[1], __ATOMIC_ACQUIRE, __HIP_MEMORY_SCOPE_AGENT) < SF_BLOCKS)
            __builtin_amdgcn_s_sleep(2);
    }
    __syncthreads();

    // phase3: atomic-free CSR fill (4B entries: src<<16 | bf16(weight))
    for (int q = bid * 256 + tid; q < RE; q += SF_BLOCKS * 256) {
        int r = q / N_EDGE;
        int s = src[q], t = dst[q];
        float wv = odeg[r * N_NODES + s] * ideg[r * N_NODES + t];
        int slot = roff[r * N_NODES + t] + (int)rank[q];
        csr[slot] = ((unsigned)s << 16) | (unsigned)f2bf(wv);
    }
}

// ---------------- gather aggregation, layer 1 (D=128), 4B CSR, unroll-8 ----------------
// LDS-free, high-occupancy (the latency-bound gather NEEDS ~8 blocks/CU — round-12
// lesson: fusing this with a 50KB-LDS GEMM drops to 3 blocks/CU and runs 2.5x slower).
// Epilogue: bias + ReLU, write h as bf16 packed.
__global__ __launch_bounds__(256) void agg128_kernel(
    const unsigned* __restrict__ Y, const unsigned* __restrict__ csr,
    const int* __restrict__ off, const int* __restrict__ roff,
    const float* __restrict__ b, unsigned* __restrict__ hbf)
{
    int wid  = (blockIdx.x * 256 + threadIdx.x) >> 6;
    int lane = threadIdx.x & 63;
    if (wid >= N_NODES) return;

    int e   = off[wid], end = off[wid + 1];
    int r1  = roff[N_NODES + wid];
    int r2  = roff[2 * N_NODES + wid];
    float a0 = 0.f, a1 = 0.f;

    for (; e + 8 <= end; e += 8) {
        unsigned p[8]; unsigned y[8];
        #pragma unroll
        for (int j = 0; j < 8; ++j) p[j] = csr[e + j];
        #pragma unroll
        for (int j = 0; j < 8; ++j) {
            int rr = (e + j >= r1) + (e + j >= r2);
            y[j] = Y[((size_t)rr * N_NODES + (p[j] >> 16)) * 64 + lane];
        }
        #pragma unroll
        for (int j = 0; j < 8; ++j) {
            float wv = __uint_as_float((p[j] & 0xffffu) << 16);
            a0 = fmaf(wv, __uint_as_float(y[j] << 16), a0);
            a1 = fmaf(wv, __uint_as_float(y[j] & 0xffff0000u), a1);
        }
    }
    if (e + 4 <= end) {
        unsigned p[4]; unsigned y[4];
        #pragma unroll
        for (int j = 0; j < 4; ++j) p[j] = csr[e + j];
        #pragma unroll
        for (int j = 0; j < 4; ++j) {
            int rr = (e + j >= r1) + (e + j >= r2);
            y[j] = Y[((size_t)rr * N_NODES + (p[j] >> 16)) * 64 + lane];
        }
        #pragma unroll
        for (int j = 0; j < 4; ++j) {
            float wv = __uint_as_float((p[j] & 0xffffu) << 16);
            a0 = fmaf(wv, __uint_as_float(y[j] << 16), a0);
            a1 = fmaf(wv, __uint_as_float(y[j] & 0xffff0000u), a1);
        }
        e += 4;
    }
    for (; e < end; ++e) {
        unsigned p = csr[e];
        int rr = (e >= r1) + (e >= r2);
        unsigned y = Y[((size_t)rr * N_NODES + (p >> 16)) * 64 + lane];
        float wv = __uint_as_float((p & 0xffffu) << 16);
        a0 = fmaf(wv, __uint_as_float(y << 16), a0);
        a1 = fmaf(wv, __uint_as_float(y & 0xffff0000u), a1);
    }

    int d = lane * 2;
    float o0 = a0 + b[d]     + b[128 + d]     + b[256 + d];
    float o1 = a1 + b[d + 1] + b[128 + d + 1] + b[256 + d + 1];
    hbf[(size_t)wid * 64 + lane] = pack_bf2(fmaxf(o0, 0.f), fmaxf(o1, 0.f));
}

// ---------------- standalone MFMA GEMM (layer 2): A staged in LDS, W dbuf ----------------
template <bool ABF16, int NCOLS>
__global__ __launch_bounds__(256) void gemm_mfma(
    const void* __restrict__ Av, const unsigned short* __restrict__ Wtf,
    unsigned short* __restrict__ Y, int nrows)
{
    __shared__ unsigned As[64 * 68];
    __shared__ unsigned Ws[2][4096];

    const int tid = threadIdx.x;
    const int mt  = blockIdx.x * 64;
    const uint4* Wt4 = (const uint4*)Wtf;

    if constexpr (ABF16) {
        const uint4* Ab = (const uint4*)Av;
        #pragma unroll
        for (int p = 0; p < 4; ++p) {
            int q   = p * 256 + tid;
            int row = q >> 4, w4 = q & 15;
            int gr  = mt + row;
            uint4 v = make_uint4(0u, 0u, 0u, 0u);
            if (gr < nrows) v = Ab[(size_t)gr * 16 + w4];
            As[row * 68 + w4 * 4 + 0] = v.x;
            As[row * 68 + w4 * 4 + 1] = v.y;
            As[row * 68 + w4 * 4 + 2] = v.z;
            As[row * 68 + w4 * 4 + 3] = v.w;
        }
    } else {
        const float* A = (const float*)Av;
        #pragma unroll
        for (int p = 0; p < 16; ++p) {
            int q   = tid + p * 256;
            int row = q >> 6, wc = q & 63;
            int gr  = mt + row;
            float2 v = make_float2(0.f, 0.f);
            if (gr < nrows) v = *reinterpret_cast<const float2*>(&A[(size_t)gr * 128 + wc * 2]);
            As[row * 68 + wc] = pack_bf2(v.x, v.y);
        }
    }

    #pragma unroll
    for (int p = 0; p < 4; ++p) {
        uint4 v = Wt4[tid + p * 256];
        *reinterpret_cast<uint4*>(&Ws[0][(tid + p * 256) * 4]) = v;
    }
    __syncthreads();

    const int w  = tid >> 6;
    const int l  = tid & 63;
    const int g  = l >> 4;
    const int lr = l & 15;
    const int ar = w * 16 + lr;

    bf16x8 a[4];
    #pragma unroll
    for (int kb = 0; kb < 4; ++kb)
        a[kb] = *reinterpret_cast<const bf16x8*>(&As[ar * 68 + kb * 16 + g * 4]);

    constexpr int TPR  = NCOLS / 16;
    constexpr int NGRP = 3 * NCOLS / 64;
    const int boff = (g * 16 + lr) * 4;

    int cur = 0;
    #pragma unroll 1
    for (int grp = 0; grp < NGRP; ++grp) {
        uint4 st[4];
        if (grp + 1 < NGRP) {
            #pragma unroll
            for (int p = 0; p < 4; ++p)
                st[p] = Wt4[(grp + 1) * 1024 + tid + p * 256];
        }

        f32x4 acc[4];
        #pragma unroll
        for (int ct4 = 0; ct4 < 4; ++ct4) {
            acc[ct4] = (f32x4){0.f, 0.f, 0.f, 0.f};
            #pragma unroll
            for (int kb = 0; kb < 4; ++kb) {
                bf16x8 b = *reinterpret_cast<const bf16x8*>(
                    &Ws[cur][(ct4 * 4 + kb) * 256 + boff]);
                acc[ct4] = __builtin_amdgcn_mfma_f32_16x16x32_bf16(a[kb], b, acc[ct4], 0, 0, 0);
            }
        }

        int gct0 = grp * 4;
        int rel  = gct0 / TPR;
        int cb   = (gct0 % TPR) * 16;
        #pragma unroll
        for (int i = 0; i < 4; ++i) {
            int grow = mt + w * 16 + g * 4 + i;
            if (grow < nrows) {
                size_t rowbase = ((size_t)rel * N_NODES + grow) * NCOLS + cb;
                #pragma unroll
                for (int ct4 = 0; ct4 < 4; ++ct4)
                    Y[rowbase + ct4 * 16 + lr] = f2bf(acc[ct4][i]);
            }
        }

        if (grp + 1 < NGRP) {
            #pragma unroll
            for (int p = 0; p < 4; ++p)
                *reinterpret_cast<uint4*>(&Ws[cur ^ 1][(tid + p * 256) * 4]) = st[p];
        }
        __syncthreads();
        cur ^= 1;
    }
}

// ---------------- gather aggregation, layer 2 output (D=64), 4B CSR, unroll-8 ----------------
__global__ __launch_bounds__(256) void agg64_kernel(
    const unsigned short* __restrict__ Y, const unsigned* __restrict__ csr,
    const int* __restrict__ off, const int* __restrict__ roff,
    const float* __restrict__ b, float* __restrict__ out)
{
    int wid  = (blockIdx.x * 256 + threadIdx.x) >> 6;
    int lane = threadIdx.x & 63;
    if (wid >= N_NODES) return;

    int e   = off[wid], end = off[wid + 1];
    int r1  = roff[N_NODES + wid];
    int r2  = roff[2 * N_NODES + wid];
    float a = 0.f;

    for (; e + 8 <= end; e += 8) {
        unsigned p[8]; unsigned short y[8];
        #pragma unroll
        for (int j = 0; j < 8; ++j) p[j] = csr[e + j];
        #pragma unroll
        for (int j = 0; j < 8; ++j) {
            int rr = (e + j >= r1) + (e + j >= r2);
            y[j] = Y[((size_t)rr * N_NODES + (p[j] >> 16)) * 64 + lane];
        }
        #pragma unroll
        for (int j = 0; j < 8; ++j)
            a = fmaf(__uint_as_float((p[j] & 0xffffu) << 16),
                     __uint_as_float(((unsigned)y[j]) << 16), a);
    }
    if (e + 4 <= end) {
        unsigned p[4]; unsigned short y[4];
        #pragma unroll
        for (int j = 0; j < 4; ++j) p[j] = csr[e + j];
        #pragma unroll
        for (int j = 0; j < 4; ++j) {
            int rr = (e + j >= r1) + (e + j >= r2);
            y[j] = Y[((size_t)rr * N_NODES + (p[j] >> 16)) * 64 + lane];
        }
        #pragma unroll
        for (int j = 0; j < 4; ++j)
            a = fmaf(__uint_as_float((p[j] & 0xffffu) << 16),
                     __uint_as_float(((unsigned)y[j]) << 16), a);
        e += 4;
    }
    for (; e < end; ++e) {
        unsigned p = csr[e];
        int rr = (e >= r1) + (e >= r2);
        a = fmaf(__uint_as_float((p & 0xffffu) << 16),
                 __uint_as_float(((unsigned)Y[((size_t)rr * N_NODES + (p >> 16)) * 64 + lane]) << 16), a);
    }

    float bs = b[lane] + b[64 + lane] + b[128 + lane];
    out[(size_t)wid * 64 + lane] = a + bs;
}

extern "C" void kernel_launch(void* const* d_in, const int* in_sizes, int n_in,
                              void* d_out, int out_size, void* d_ws, size_t ws_size,
                              hipStream_t stream)
{
    const float* x   = (const float*)d_in[0];   // [N,128]
    const float* W1  = (const float*)d_in[1];   // [3,128,128]
    const float* b1  = (const float*)d_in[2];   // [3,128]
    const float* W2  = (const float*)d_in[3];   // [3,128,64]
    const float* b2  = (const float*)d_in[4];   // [3,64]
    const int*   src = (const int*)d_in[5];     // [3,E]
    const int*   dst = (const int*)d_in[6];     // [3,E]
    float*       out = (float*)d_out;           // [N,64]

    // workspace layout
    char* w = (char*)d_ws;
    float* onorm  = (float*)w;                 w += (size_t)RN * 4;           // counts then norms
    float* inorm  = (float*)w;                 w += (size_t)RN * 4;           // counts then norms
    int*   off    = (int*)w;                   w += (size_t)(N_NODES + 1) * 4;
    int*   roff   = (int*)w;                   w += (size_t)RN * 4;
    int*   bsums  = (int*)w;                   w += 1024;
    int*   done   = (int*)w;                   w += 512;
    unsigned short* rank = (unsigned short*)w; w += (size_t)RE * 2;
    w = (char*)(((uintptr_t)w + 255) & ~(uintptr_t)255);
    unsigned* csr = (unsigned*)w;              w += (size_t)RE * 4;
    unsigned* hbf = (unsigned*)w;              w += (size_t)N_NODES * 64 * 4; // bf16 h [N,128]
    unsigned short* Ybf = (unsigned short*)w;  w += (size_t)N_REL * N_NODES * 128 * 2;
    unsigned short* Wt1 = (unsigned short*)w;  w += (size_t)N_REL * 128 * 128 * 2;
    unsigned short* Wt2 = (unsigned short*)w;  // 3*64*128*2

    // 0) prep: weight convert + zero counters + zero spin flags
    prep_kernel<<<PREP_BLKS, 256, 0, stream>>>(W1, Wt1, W2, Wt2, onorm, done);

    // 1) FUSED interleaved: gemm1 (x@W1 -> Ybf) + degrees + ranks
    fused_gemm1_deg<<<FUSE_CHUNKS * 32, 256, 0, stream>>>(
        x, Wt1, Ybf, src, dst, onorm, inorm, rank);

    // 2) FUSED scan+fill: off/roff + norms + atomic-free CSR fill (spin-synced)
    scan_fill_kernel<<<SF_BLOCKS, 256, 0, stream>>>(
        onorm, inorm, off, roff, bsums, done, src, dst, rank, csr);

    // 3) layer-1 aggregate (LDS-free, max occupancy) + bias + ReLU -> hbf (bf16)
    agg128_kernel<<<(N_NODES + 3) / 4, 256, 0, stream>>>(
        (const unsigned*)Ybf, csr, off, roff, b1, hbf);

    // 4) layer 2: Y_r = hbf @ W2_r (bf16, MFMA; Ybf dead after agg128 -> safe reuse)
    gemm_mfma<true, 64><<<GEMM1_BLKS, 256, 0, stream>>>(hbf, Wt2, Ybf, N_NODES);

    // 5) final aggregation into out
    agg64_kernel<<<(N_NODES + 3) / 4, 256, 0, stream>>>(Ybf, csr, off, roff, b2, out);
}